// Round 1
// baseline (373.685 us; speedup 1.0000x reference)
//
#include <hip/hip_runtime.h>

#define B_ 4
#define T_ 4096
#define DM 512
#define DH 64

typedef short short8 __attribute__((ext_vector_type(8)));
typedef float f32x4 __attribute__((ext_vector_type(4)));
typedef float float8 __attribute__((ext_vector_type(8)));

__device__ inline short f2bf(float f) {
    unsigned u = __float_as_uint(f);
    u += 0x7fffu + ((u >> 16) & 1u);
    return (short)(u >> 16);
}

__device__ inline short8 cvt8(const float* p) {
    float8 v = *(const float8*)p;
    short8 r;
#pragma unroll
    for (int j = 0; j < 8; j++) r[j] = f2bf(v[j]);
    return r;
}

// ---------------- Kernel 1: q,k,v projections ----------------
// grid = B*T/64 blocks, 256 threads (4 waves x 16 rows)
__global__ __launch_bounds__(256) void k_proj(
    const float* __restrict__ x, const float* __restrict__ Wq,
    const float* __restrict__ Wk, const float* __restrict__ Wv,
    short* __restrict__ qb, short* __restrict__ kb, float* __restrict__ v32)
{
    int tid = threadIdx.x;
    int lane = tid & 63, w = tid >> 6;
    int l16 = lane & 15, quad = lane >> 4;
    int b = blockIdx.x >> 6;        // 64 tiles of 64 rows per batch
    int tile = blockIdx.x & 63;
    int t0w = tile * 64 + w * 16;
    long base_x = ((long)(b * T_ + t0w + l16)) * DM;

    f32x4 accq[4], acck[4], accv[4];
#pragma unroll
    for (int i = 0; i < 4; i++) { accq[i] = (f32x4)(0.f); acck[i] = (f32x4)(0.f); accv[i] = (f32x4)(0.f); }

    for (int kc = 0; kc < DM; kc += 32) {
        short8 af = cvt8(x + base_x + kc + quad * 8);   // A[m=t][k=d]
#pragma unroll
        for (int h4 = 0; h4 < 4; h4++) {
            int h = h4 * 16 + l16;
            long wo = (long)h * DM + kc + quad * 8;
            accq[h4] = __builtin_amdgcn_mfma_f32_16x16x32_bf16(af, cvt8(Wq + wo), accq[h4], 0, 0, 0);
            acck[h4] = __builtin_amdgcn_mfma_f32_16x16x32_bf16(af, cvt8(Wk + wo), acck[h4], 0, 0, 0);
            accv[h4] = __builtin_amdgcn_mfma_f32_16x16x32_bf16(af, cvt8(Wv + wo), accv[h4], 0, 0, 0);
        }
    }
#pragma unroll
    for (int h4 = 0; h4 < 4; h4++)
#pragma unroll
        for (int r = 0; r < 4; r++) {
            int t = t0w + quad * 4 + r;
            long o = ((long)(b * T_ + t)) * DH + h4 * 16 + l16;
            qb[o] = f2bf(accq[h4][r]);
            kb[o] = f2bf(acck[h4][r]);
            v32[o] = accv[h4][r];
        }
}

// ---------------- Kernel 2: column sums l[s] = sum_{t>=s} exp(z[t,s]) ----------------
// grid = B*64 blocks, 256 threads; block pairs low/high column tiles for balance
__global__ __launch_bounds__(256) void k_stats(
    const short* __restrict__ qb, const short* __restrict__ kb, float* __restrict__ lsum)
{
    int tid = threadIdx.x;
    int lane = tid & 63, w = tid >> 6;
    int l16 = lane & 15, quad = lane >> 4;
    int b = blockIdx.x >> 6;
    int j = blockIdx.x & 63;
    int s0w = (w < 2) ? (j * 32 + w * 16) : (T_ - j * 32 - 32 + (w - 2) * 16);
    long bq = (long)b * T_ * DH;

    const short8* ka = (const short8*)(kb + bq + (long)(s0w + l16) * DH + quad * 8);
    short8 a0 = ka[0];   // A[m=s][k=h], h 0..31
    short8 a1 = ka[4];   // h 32..63

    float acc[4] = {0.f, 0.f, 0.f, 0.f};
    const float SC = 0.125f;
    for (int t0 = s0w; t0 < T_; t0 += 16) {
        const short8* qp = (const short8*)(qb + bq + (long)(t0 + l16) * DH + quad * 8);
        short8 b0 = qp[0], b1 = qp[4];
        f32x4 d = (f32x4)(0.f);
        d = __builtin_amdgcn_mfma_f32_16x16x32_bf16(a0, b0, d, 0, 0, 0);
        d = __builtin_amdgcn_mfma_f32_16x16x32_bf16(a1, b1, d, 0, 0, 0);
        int t = t0 + l16;                      // D: row = s (quad*4+r), col = t (l16)
#pragma unroll
        for (int r = 0; r < 4; r++) {
            int s = s0w + quad * 4 + r;
            float p = __expf(d[r] * SC);
            acc[r] += (t >= s) ? p : 0.f;
        }
    }
#pragma unroll
    for (int r = 0; r < 4; r++) {
        float v = acc[r];
        v += __shfl_xor(v, 1, 16);
        v += __shfl_xor(v, 2, 16);
        v += __shfl_xor(v, 4, 16);
        v += __shfl_xor(v, 8, 16);
        if (l16 == 0) lsum[b * T_ + s0w + quad * 4 + r] = v;
    }
}

// ---------------- Kernel 3: vT[b][h][s] = bf16(v[b][s][h] / l[s]) ----------------
__global__ __launch_bounds__(256) void k_vt(
    const float* __restrict__ v32, const float* __restrict__ lsum, short* __restrict__ vT)
{
    int s = blockIdx.x * 256 + threadIdx.x;   // global row index over B*T
    int b = s >> 12;
    int sl = s & (T_ - 1);
    float rl = 1.0f / lsum[s];
    long vb = (long)s * DH;
    long ob = (long)b * DH * T_ + sl;
    for (int h = 0; h < DH; h++)
        vT[ob + (long)h * T_] = f2bf(v32[vb + h] * rl);
}

// ---------------- Kernel 4: out[t] = sum_{s<=t} exp(z[t,s]) * vT[:,s] ----------------
// grid = B*64 blocks, 256 threads; block pairs low/high row tiles for balance
__global__ __launch_bounds__(256) void k_out(
    const short* __restrict__ qb, const short* __restrict__ kb,
    const short* __restrict__ vT, float* __restrict__ out)
{
    __shared__ short pt[4][16 * 40];   // per-wave P tile, padded stride 40
    int tid = threadIdx.x;
    int lane = tid & 63, w = tid >> 6;
    int l16 = lane & 15, quad = lane >> 4;
    int b = blockIdx.x >> 6;
    int j = blockIdx.x & 63;
    int t0w = (w < 2) ? (j * 32 + w * 16) : (T_ - j * 32 - 32 + (w - 2) * 16);
    long bq = (long)b * T_ * DH;

    const short8* qp = (const short8*)(qb + bq + (long)(t0w + l16) * DH + quad * 8);
    short8 aq0 = qp[0], aq1 = qp[4];   // A[m=t][k=h]

    f32x4 o0 = (f32x4)(0.f), o1 = o0, o2 = o0, o3 = o0;
    const float SC = 0.125f;
    short* myp = pt[w];
    long vbase = (long)b * DH * T_;
    int tmax = t0w + 15;

    for (int sc = 0; sc <= tmax; sc += 32) {
#pragma unroll
        for (int sh = 0; sh < 2; sh++) {
            int s0h = sc + sh * 16;
            if (s0h <= tmax) {
                const short8* kp = (const short8*)(kb + bq + (long)(s0h + l16) * DH + quad * 8);
                short8 b0 = kp[0], b1 = kp[4];
                f32x4 d = (f32x4)(0.f);
                d = __builtin_amdgcn_mfma_f32_16x16x32_bf16(aq0, b0, d, 0, 0, 0);
                d = __builtin_amdgcn_mfma_f32_16x16x32_bf16(aq1, b1, d, 0, 0, 0);
                int s = s0h + l16;             // D: row = t (quad*4+r), col = s (l16)
#pragma unroll
                for (int r = 0; r < 4; r++) {
                    int t = t0w + quad * 4 + r;
                    float p = __expf(d[r] * SC);
                    p = (s <= t) ? p : 0.f;
                    myp[(quad * 4 + r) * 40 + sh * 16 + l16] = f2bf(p);
                }
            } else {
#pragma unroll
                for (int r = 0; r < 4; r++)
                    myp[(quad * 4 + r) * 40 + sh * 16 + l16] = 0;
            }
        }
        // wave-private LDS round-trip: C-layout -> A-layout
        asm volatile("s_waitcnt lgkmcnt(0)" ::: "memory");
        short8 ap = *(const short8*)(myp + l16 * 40 + quad * 8);   // A[m=t][k=s_local]
#pragma unroll
        for (int h4 = 0; h4 < 4; h4++) {
            const short8* vp = (const short8*)(vT + vbase + (long)(h4 * 16 + l16) * T_ + sc + quad * 8);
            short8 bv = vp[0];                 // B[k=s][n=h]
            f32x4 acc = (h4 == 0) ? o0 : (h4 == 1) ? o1 : (h4 == 2) ? o2 : o3;
            acc = __builtin_amdgcn_mfma_f32_16x16x32_bf16(ap, bv, acc, 0, 0, 0);
            if (h4 == 0) o0 = acc; else if (h4 == 1) o1 = acc; else if (h4 == 2) o2 = acc; else o3 = acc;
        }
    }

    f32x4 oo[4] = {o0, o1, o2, o3};
#pragma unroll
    for (int h4 = 0; h4 < 4; h4++)
#pragma unroll
        for (int r = 0; r < 4; r++) {
            int t = t0w + quad * 4 + r;
            out[bq + (long)t * DH + h4 * 16 + l16] = oo[h4][r];
        }
}

extern "C" void kernel_launch(void* const* d_in, const int* in_sizes, int n_in,
                              void* d_out, int out_size, void* d_ws, size_t ws_size,
                              hipStream_t stream) {
    const float* x  = (const float*)d_in[0];
    const float* Wq = (const float*)d_in[1];
    const float* Wk = (const float*)d_in[2];
    const float* Wv = (const float*)d_in[3];
    float* out = (float*)d_out;

    char* ws = (char*)d_ws;
    short* qb   = (short*)(ws);                    // 2 MB  bf16 [B,T,64]
    short* kb   = (short*)(ws + (2l << 20));       // 2 MB  bf16 [B,T,64]
    float* v32  = (float*)(ws + (4l << 20));       // 4 MB  fp32 [B,T,64]
    short* vT   = (short*)(ws + (8l << 20));       // 2 MB  bf16 [B,64,T]
    float* lsum = (float*)(ws + (10l << 20));      // 64 KB fp32 [B,T]

    k_proj<<<dim3(B_ * T_ / 64), dim3(256), 0, stream>>>(x, Wq, Wk, Wv, qb, kb, v32);
    k_stats<<<dim3(B_ * 64), dim3(256), 0, stream>>>(qb, kb, lsum);
    k_vt<<<dim3(B_ * T_ / 256), dim3(256), 0, stream>>>(v32, lsum, vT);
    k_out<<<dim3(B_ * 64), dim3(256), 0, stream>>>(qb, kb, vT, out);
}

// Round 2
// 294.111 us; speedup vs baseline: 1.2706x; 1.2706x over previous
//
#include <hip/hip_runtime.h>

#define B_ 4
#define T_ 4096
#define DM 512
#define DH 64
#define CS 512     // s-chunk for k_out
#define CSS 512    // t-chunk for k_stats

typedef short short8 __attribute__((ext_vector_type(8)));
typedef float f32x4 __attribute__((ext_vector_type(4)));
typedef float float8 __attribute__((ext_vector_type(8)));

__device__ inline short f2bf(float f) {
    unsigned u = __float_as_uint(f);
    u += 0x7fffu + ((u >> 16) & 1u);
    return (short)(u >> 16);
}
__device__ inline float bf2f(short s) {
    return __uint_as_float(((unsigned)(unsigned short)s) << 16);
}
__device__ inline short8 cvt8(const float* p) {
    float8 v = *(const float8*)p;
    short8 r;
#pragma unroll
    for (int j = 0; j < 8; j++) r[j] = f2bf(v[j]);
    return r;
}

// ---------------- Kernel 0: convert Wq|Wk|Wv (fp32) -> wb (bf16, concat) ----------------
// 3*64*512 = 98304 elements; 48 blocks x 256 threads x 8 elem
__global__ __launch_bounds__(256) void k_wcvt(
    const float* __restrict__ Wq, const float* __restrict__ Wk,
    const float* __restrict__ Wv, short* __restrict__ wb)
{
    int e = (blockIdx.x * 256 + threadIdx.x) * 8;
    int m = e / (DH * DM);
    int off = e - m * (DH * DM);
    const float* W = (m == 0) ? Wq : (m == 1) ? Wk : Wv;
    *(short8*)(wb + e) = cvt8(W + off);
}

// ---------------- Kernel 1: q,k,v projections (one matrix per block-slice) ----------------
// grid = 3 * B*T/64, 256 threads (4 waves x 16 rows)
__global__ __launch_bounds__(256) void k_proj(
    const float* __restrict__ x, const short* __restrict__ wb,
    short* __restrict__ qb, short* __restrict__ kb, short* __restrict__ vb)
{
    int tid = threadIdx.x;
    int lane = tid & 63, w = tid >> 6;
    int l16 = lane & 15, quad = lane >> 4;
    int r = blockIdx.x % (B_ * T_ / 64);
    int m = blockIdx.x / (B_ * T_ / 64);
    int b = r >> 6, tile = r & 63;
    int t0w = tile * 64 + w * 16;
    long base_x = ((long)(b * T_ + t0w + l16)) * DM;
    const short* W = wb + m * DH * DM;
    short* outp = (m == 0) ? qb : (m == 1) ? kb : vb;

    f32x4 acc[4];
#pragma unroll
    for (int i = 0; i < 4; i++) acc[i] = (f32x4)(0.f);

    for (int kc = 0; kc < DM; kc += 32) {
        short8 af = cvt8(x + base_x + kc + quad * 8);   // A[m=t][k=d]
#pragma unroll
        for (int h4 = 0; h4 < 4; h4++) {
            short8 bf = *(const short8*)(W + (long)(h4 * 16 + l16) * DM + kc + quad * 8);
            acc[h4] = __builtin_amdgcn_mfma_f32_16x16x32_bf16(af, bf, acc[h4], 0, 0, 0);
        }
    }
#pragma unroll
    for (int h4 = 0; h4 < 4; h4++)
#pragma unroll
        for (int r4 = 0; r4 < 4; r4++) {
            int t = t0w + quad * 4 + r4;
            outp[((long)(b * T_ + t)) * DH + h4 * 16 + l16] = f2bf(acc[h4][r4]);
        }
}

// ---------------- Kernel 2: partial column sums l[s] += sum_{t in chunk, t>=s} exp(z) ----------------
// grid = B * 64 * (T/CSS), 256 threads
__global__ __launch_bounds__(256) void k_stats(
    const short* __restrict__ qb, const short* __restrict__ kb, float* __restrict__ lsum)
{
    int tid = threadIdx.x;
    int lane = tid & 63, w = tid >> 6;
    int l16 = lane & 15, quad = lane >> 4;
    const int NC = T_ / CSS;
    int chunk = blockIdx.x % NC;
    int ct = (blockIdx.x / NC) & 63;
    int b = blockIdx.x / (NC * 64);
    int t_end = chunk * CSS + CSS;
    if (t_end <= ct * 64) return;           // whole block idle
    int s0w = ct * 64 + w * 16;
    if (t_end <= s0w) return;               // this wave idle
    int t_begin = (chunk * CSS > s0w) ? chunk * CSS : s0w;
    long bq = (long)b * T_ * DH;

    const short8* ka = (const short8*)(kb + bq + (long)(s0w + l16) * DH + quad * 8);
    short8 a0 = ka[0];   // A[m=s][k=h], h 0..31
    short8 a1 = ka[4];   // h 32..63

    float acc[4] = {0.f, 0.f, 0.f, 0.f};
    const float SC = 0.125f;
    for (int t0 = t_begin; t0 < t_end; t0 += 16) {
        const short8* qp = (const short8*)(qb + bq + (long)(t0 + l16) * DH + quad * 8);
        short8 b0 = qp[0], b1 = qp[4];
        f32x4 d = (f32x4)(0.f);
        d = __builtin_amdgcn_mfma_f32_16x16x32_bf16(a0, b0, d, 0, 0, 0);
        d = __builtin_amdgcn_mfma_f32_16x16x32_bf16(a1, b1, d, 0, 0, 0);
        int t = t0 + l16;                    // D: row = s (quad*4+r), col = t (l16)
#pragma unroll
        for (int r = 0; r < 4; r++) {
            int s = s0w + quad * 4 + r;
            float p = __expf(d[r] * SC);
            acc[r] += (t >= s) ? p : 0.f;
        }
    }
#pragma unroll
    for (int r = 0; r < 4; r++) {
        float v = acc[r];
        v += __shfl_xor(v, 1, 16);
        v += __shfl_xor(v, 2, 16);
        v += __shfl_xor(v, 4, 16);
        v += __shfl_xor(v, 8, 16);
        if (l16 == 0) atomicAdd(&lsum[b * T_ + s0w + quad * 4 + r], v);
    }
}

// ---------------- Kernel 3: vT[b][h][s] = bf16(v[b][s][h] / l[s]) via LDS transpose ----------------
// grid = B*T/64, 256 threads; block handles 64 s-rows
__global__ __launch_bounds__(256) void k_vt(
    const short* __restrict__ vb, const float* __restrict__ lsum, short* __restrict__ vT)
{
    __shared__ float tile[64][65];
    int tid = threadIdx.x;
    int b = blockIdx.x >> 6;
    int s0 = (blockIdx.x & 63) * 64;
    int h = tid & 63;
#pragma unroll
    for (int i = 0; i < 16; i++) {
        int s = (tid >> 6) + i * 4;
        tile[s][h] = bf2f(vb[((long)(b * T_ + s0 + s)) * DH + h]);
    }
    __syncthreads();
    int sl = tid & 63;
    float rl = 1.0f / lsum[b * T_ + s0 + sl];
    long ob = (long)b * DH * T_ + s0 + sl;
#pragma unroll
    for (int i = 0; i < 16; i++) {
        int hh = (tid >> 6) + i * 4;
        vT[ob + (long)hh * T_] = f2bf(tile[sl][hh] * rl);
    }
}

// ---------------- Kernel 4: out[t] += sum_{s in chunk, s<=t} exp(z) * vT[:,s] ----------------
// grid = B * 64 * (T/CS), 256 threads; atomic fp32 accumulation into out
__global__ __launch_bounds__(256) void k_out(
    const short* __restrict__ qb, const short* __restrict__ kb,
    const short* __restrict__ vT, float* __restrict__ out)
{
    __shared__ short pt[4][16 * 40];   // per-wave P tile, padded stride 40
    int tid = threadIdx.x;
    int lane = tid & 63, w = tid >> 6;
    int l16 = lane & 15, quad = lane >> 4;
    const int NC = T_ / CS;
    int chunk = blockIdx.x % NC;
    int rt = (blockIdx.x / NC) & 63;
    int b = blockIdx.x / (NC * 64);
    int c0 = chunk * CS;
    if (c0 > rt * 64 + 63) return;      // whole block idle
    int t0w = rt * 64 + w * 16;
    int tmax = t0w + 15;
    if (c0 > tmax) return;              // this wave idle
    int s_end = (c0 + CS < tmax + 1) ? c0 + CS : tmax + 1;
    long bq = (long)b * T_ * DH;

    const short8* qp = (const short8*)(qb + bq + (long)(t0w + l16) * DH + quad * 8);
    short8 aq0 = qp[0], aq1 = qp[4];   // A[m=t][k=h]

    f32x4 o0 = (f32x4)(0.f), o1 = o0, o2 = o0, o3 = o0;
    const float SC = 0.125f;
    short* myp = pt[w];
    long vbase = (long)b * DH * T_;

    for (int sc = c0; sc < s_end; sc += 32) {
#pragma unroll
        for (int sh = 0; sh < 2; sh++) {
            int s0h = sc + sh * 16;
            if (s0h < s_end) {
                const short8* kp = (const short8*)(kb + bq + (long)(s0h + l16) * DH + quad * 8);
                short8 b0 = kp[0], b1 = kp[4];
                f32x4 d = (f32x4)(0.f);
                d = __builtin_amdgcn_mfma_f32_16x16x32_bf16(aq0, b0, d, 0, 0, 0);
                d = __builtin_amdgcn_mfma_f32_16x16x32_bf16(aq1, b1, d, 0, 0, 0);
                int s = s0h + l16;             // D: row = t (quad*4+r), col = s (l16)
#pragma unroll
                for (int r = 0; r < 4; r++) {
                    int t = t0w + quad * 4 + r;
                    float p = __expf(d[r] * SC);
                    p = (s <= t) ? p : 0.f;
                    myp[(quad * 4 + r) * 40 + sh * 16 + l16] = f2bf(p);
                }
            } else {
#pragma unroll
                for (int r = 0; r < 4; r++)
                    myp[(quad * 4 + r) * 40 + sh * 16 + l16] = 0;
            }
        }
        // wave-private LDS round-trip: C-layout -> A-layout
        asm volatile("s_waitcnt lgkmcnt(0)" ::: "memory");
        short8 ap = *(const short8*)(myp + l16 * 40 + quad * 8);   // A[m=t][k=s_local]
#pragma unroll
        for (int h4 = 0; h4 < 4; h4++) {
            const short8* vp = (const short8*)(vT + vbase + (long)(h4 * 16 + l16) * T_ + sc + quad * 8);
            short8 bv = vp[0];                 // B[k=s][n=h]
            f32x4 acc = (h4 == 0) ? o0 : (h4 == 1) ? o1 : (h4 == 2) ? o2 : o3;
            acc = __builtin_amdgcn_mfma_f32_16x16x32_bf16(ap, bv, acc, 0, 0, 0);
            if (h4 == 0) o0 = acc; else if (h4 == 1) o1 = acc; else if (h4 == 2) o2 = acc; else o3 = acc;
        }
    }

    f32x4 oo[4] = {o0, o1, o2, o3};
#pragma unroll
    for (int h4 = 0; h4 < 4; h4++)
#pragma unroll
        for (int r = 0; r < 4; r++) {
            int t = t0w + quad * 4 + r;
            atomicAdd(&out[bq + (long)t * DH + h4 * 16 + l16], oo[h4][r]);
        }
}

extern "C" void kernel_launch(void* const* d_in, const int* in_sizes, int n_in,
                              void* d_out, int out_size, void* d_ws, size_t ws_size,
                              hipStream_t stream) {
    const float* x  = (const float*)d_in[0];
    const float* Wq = (const float*)d_in[1];
    const float* Wk = (const float*)d_in[2];
    const float* Wv = (const float*)d_in[3];
    float* out = (float*)d_out;

    char* ws = (char*)d_ws;
    short* qb   = (short*)(ws);                    // 2 MB  bf16 [B,T,64]
    short* kb   = (short*)(ws + (2l << 20));       // 2 MB  bf16 [B,T,64]
    short* vb   = (short*)(ws + (4l << 20));       // 2 MB  bf16 [B,T,64]
    short* vT   = (short*)(ws + (6l << 20));       // 2 MB  bf16 [B,64,T]
    short* wb   = (short*)(ws + (8l << 20));       // 192 KB bf16 [3,64,512]
    float* lsum = (float*)(ws + (9l << 20));       // 64 KB fp32 [B,T]

    hipMemsetAsync(out, 0, (size_t)out_size * sizeof(float), stream);
    hipMemsetAsync(lsum, 0, (size_t)(B_ * T_) * sizeof(float), stream);

    k_wcvt<<<dim3(48), dim3(256), 0, stream>>>(Wq, Wk, Wv, wb);
    k_proj<<<dim3(3 * B_ * T_ / 64), dim3(256), 0, stream>>>(x, wb, qb, kb, vb);
    k_stats<<<dim3(B_ * 64 * (T_ / CSS)), dim3(256), 0, stream>>>(qb, kb, lsum);
    k_vt<<<dim3(B_ * T_ / 64), dim3(256), 0, stream>>>(vb, lsum, vT);
    k_out<<<dim3(B_ * 64 * (T_ / CS)), dim3(256), 0, stream>>>(qb, kb, vT, out);
}

// Round 3
// 180.211 us; speedup vs baseline: 2.0736x; 1.6320x over previous
//
#include <hip/hip_runtime.h>

#define B_ 4
#define T_ 4096
#define DM 512
#define DH 64
#define CS 512     // s-chunk for k_out
#define CT 1024    // t-chunk for k_stats

typedef short short8 __attribute__((ext_vector_type(8)));
typedef float f32x4 __attribute__((ext_vector_type(4)));
typedef float float8 __attribute__((ext_vector_type(8)));

__device__ inline short f2bf(float f) {
    unsigned u = __float_as_uint(f);
    u += 0x7fffu + ((u >> 16) & 1u);
    return (short)(u >> 16);
}
__device__ inline float bf2f(short s) {
    return __uint_as_float(((unsigned)(unsigned short)s) << 16);
}
__device__ inline short8 cvt8(const float* p) {
    float8 v = *(const float8*)p;
    short8 r;
#pragma unroll
    for (int j = 0; j < 8; j++) r[j] = f2bf(v[j]);
    return r;
}

// ---------------- Kernel 0: convert Wq|Wk|Wv (fp32) -> wb (bf16, concat) ----------------
__global__ __launch_bounds__(256) void k_wcvt(
    const float* __restrict__ Wq, const float* __restrict__ Wk,
    const float* __restrict__ Wv, short* __restrict__ wb)
{
    int e = (blockIdx.x * 256 + threadIdx.x) * 8;
    int m = e / (DH * DM);
    int off = e - m * (DH * DM);
    const float* W = (m == 0) ? Wq : (m == 1) ? Wk : Wv;
    *(short8*)(wb + e) = cvt8(W + off);
}

// ---------------- Kernel 1: q,k,v projections ----------------
__global__ __launch_bounds__(256) void k_proj(
    const float* __restrict__ x, const short* __restrict__ wb,
    short* __restrict__ qb, short* __restrict__ kb, short* __restrict__ vb)
{
    int tid = threadIdx.x;
    int lane = tid & 63, w = tid >> 6;
    int l16 = lane & 15, quad = lane >> 4;
    int r = blockIdx.x % (B_ * T_ / 64);
    int m = blockIdx.x / (B_ * T_ / 64);
    int b = r >> 6, tile = r & 63;
    int t0w = tile * 64 + w * 16;
    long base_x = ((long)(b * T_ + t0w + l16)) * DM;
    const short* W = wb + m * DH * DM;
    short* outp = (m == 0) ? qb : (m == 1) ? kb : vb;

    f32x4 acc[4];
#pragma unroll
    for (int i = 0; i < 4; i++) acc[i] = (f32x4)(0.f);

    for (int kc = 0; kc < DM; kc += 32) {
        short8 af = cvt8(x + base_x + kc + quad * 8);   // A[m=t][k=d]
#pragma unroll
        for (int h4 = 0; h4 < 4; h4++) {
            short8 bf = *(const short8*)(W + (long)(h4 * 16 + l16) * DM + kc + quad * 8);
            acc[h4] = __builtin_amdgcn_mfma_f32_16x16x32_bf16(af, bf, acc[h4], 0, 0, 0);
        }
    }
#pragma unroll
    for (int h4 = 0; h4 < 4; h4++)
#pragma unroll
        for (int r4 = 0; r4 < 4; r4++) {
            int t = t0w + quad * 4 + r4;
            outp[((long)(b * T_ + t)) * DH + h4 * 16 + l16] = f2bf(acc[h4][r4]);
        }
}

// ---------------- Kernel 2: partial column sums, LDS-staged Q tiles ----------------
// grid = B * 64 * (T/CT); block: 64 s-rows, t-chunk CT staged in 128-steps
__global__ __launch_bounds__(256) void k_stats(
    const short* __restrict__ qb, const short* __restrict__ kb, float* __restrict__ lsum)
{
    __shared__ short Qb[128 * 72];   // 128 t-rows x (64 + 8 pad) shorts
    int tid = threadIdx.x;
    int lane = tid & 63, w = tid >> 6;
    int l16 = lane & 15, quad = lane >> 4;
    const int NC = T_ / CT;   // 4
    int chunk = blockIdx.x % NC;
    int st64 = (blockIdx.x / NC) & 63;
    int b = blockIdx.x / (NC * 64);
    int c0 = chunk * CT;
    int s0blk = st64 * 64;
    int lim = c0 + CT;
    if (lim <= s0blk) return;               // uniform: block idle
    int t_lo = (c0 > s0blk) ? c0 : s0blk;   // multiple of 64
    int nsteps = (lim - t_lo + 127) >> 7;
    int s0w = s0blk + w * 16;
    long bq = (long)b * T_ * DH;

    const short8* ka = (const short8*)(kb + bq + (long)(s0w + l16) * DH + quad * 8);
    short8 a0 = ka[0], a1 = ka[4];          // A[m=s][k=h]

    float acc[4] = {0.f, 0.f, 0.f, 0.f};
    const float SC = 0.125f;

    for (int stp = 0; stp < nsteps; stp++) {
        int t0 = t_lo + stp * 128;
        // stage 128 q-rows (coalesced 16B per thread, 4 passes)
#pragma unroll
        for (int p = 0; p < 4; p++) {
            int idx = p * 256 + tid;
            int row = idx >> 3, col = idx & 7;
            int rr = t0 + row; rr = (rr < T_) ? rr : (T_ - 1);
            *(short8*)(Qb + row * 72 + col * 8) =
                *(const short8*)(qb + bq + (long)rr * DH + col * 8);
        }
        __syncthreads();
        int nsub = (lim - t0) >> 4; nsub = (nsub > 8) ? 8 : nsub;
        for (int sub = 0; sub < nsub; sub++) {
            int tb = t0 + sub * 16;
            if (tb + 15 < s0w) continue;    // entirely below diagonal for this wave
            int rowb = sub * 16 + l16;
            short8 b0 = *(const short8*)(Qb + rowb * 72 + quad * 8);
            short8 b1 = *(const short8*)(Qb + rowb * 72 + 32 + quad * 8);
            f32x4 d = (f32x4)(0.f);
            d = __builtin_amdgcn_mfma_f32_16x16x32_bf16(a0, b0, d, 0, 0, 0);
            d = __builtin_amdgcn_mfma_f32_16x16x32_bf16(a1, b1, d, 0, 0, 0);
            int t = tb + l16;               // D: row=s (quad*4+r), col=t (l16)
#pragma unroll
            for (int r = 0; r < 4; r++) {
                int s = s0w + quad * 4 + r;
                float p = __expf(d[r] * SC);
                acc[r] += (t >= s) ? p : 0.f;
            }
        }
        __syncthreads();
    }
#pragma unroll
    for (int r = 0; r < 4; r++) {
        float v = acc[r];
        v += __shfl_xor(v, 1, 16);
        v += __shfl_xor(v, 2, 16);
        v += __shfl_xor(v, 4, 16);
        v += __shfl_xor(v, 8, 16);
        if (l16 == 0) atomicAdd(&lsum[b * T_ + s0w + quad * 4 + r], v);
    }
}

// ---------------- Kernel 3: vT[b][h][s] = bf16(v[b][s][h] / l[s]) ----------------
__global__ __launch_bounds__(256) void k_vt(
    const short* __restrict__ vb, const float* __restrict__ lsum, short* __restrict__ vT)
{
    __shared__ float tile[64][65];
    int tid = threadIdx.x;
    int b = blockIdx.x >> 6;
    int s0 = (blockIdx.x & 63) * 64;
    int h = tid & 63;
#pragma unroll
    for (int i = 0; i < 16; i++) {
        int s = (tid >> 6) + i * 4;
        tile[s][h] = bf2f(vb[((long)(b * T_ + s0 + s)) * DH + h]);
    }
    __syncthreads();
    int sl = tid & 63;
    float rl = 1.0f / lsum[b * T_ + s0 + sl];
    long ob = (long)b * DH * T_ + s0 + sl;
#pragma unroll
    for (int i = 0; i < 16; i++) {
        int hh = (tid >> 6) + i * 4;
        vT[ob + (long)hh * T_] = f2bf(tile[sl][hh] * rl);
    }
}

// ---------------- Kernel 4: LDS-staged fused score+PV ----------------
// grid = B * 64 * (T/CS); block: 64 t-rows, s-chunk CS staged in 128-steps
__global__ __launch_bounds__(256) void k_out(
    const short* __restrict__ qb, const short* __restrict__ kb,
    const short* __restrict__ vT, float* __restrict__ out)
{
    __shared__ short Kb[128 * 72];    // 128 s-rows x (64+8) shorts   = 18432 B
    __shared__ short Vb[64 * 136];    // 64 h-rows x (128+8) shorts   = 17408 B
    __shared__ short Pt[4][16 * 40];  // per-wave P tile              =  5120 B
    int tid = threadIdx.x;
    int lane = tid & 63, w = tid >> 6;
    int l16 = lane & 15, quad = lane >> 4;
    const int NC = T_ / CS;   // 8
    int chunk = blockIdx.x % NC;
    int rt = (blockIdx.x / NC) & 63;
    int b = blockIdx.x / (NC * 64);
    int c0 = chunk * CS;
    int blk_tmax = rt * 64 + 63;
    if (c0 > blk_tmax) return;                // uniform: block idle (implies c0 <= rt*64)
    int s_hi = (c0 + CS < blk_tmax + 1) ? c0 + CS : blk_tmax + 1;
    int nsteps = (s_hi - c0 + 127) >> 7;
    int t0w = rt * 64 + w * 16;
    int tmax = t0w + 15;
    long bq = (long)b * T_ * DH;
    long vbase = (long)b * DH * T_;

    const short8* qp = (const short8*)(qb + bq + (long)(t0w + l16) * DH + quad * 8);
    short8 aq0 = qp[0], aq1 = qp[4];          // A[m=t][k=h]

    f32x4 o0 = (f32x4)(0.f), o1 = o0, o2 = o0, o3 = o0;
    const float SC = 0.125f;
    short* myp = Pt[w];

    for (int stp = 0; stp < nsteps; stp++) {
        int s0 = c0 + stp * 128;
        // stage K tile: 128 rows x 64 shorts (16 KB)
#pragma unroll
        for (int p = 0; p < 4; p++) {
            int idx = p * 256 + tid;
            int row = idx >> 3, col = idx & 7;
            *(short8*)(Kb + row * 72 + col * 8) =
                *(const short8*)(kb + bq + (long)(s0 + row) * DH + col * 8);
        }
        // stage vT tile: 64 h-rows x 128 shorts (16 KB)
#pragma unroll
        for (int p = 0; p < 4; p++) {
            int idx = p * 256 + tid;
            int row = idx >> 4, col = idx & 15;
            *(short8*)(Vb + row * 136 + col * 8) =
                *(const short8*)(vT + vbase + (long)row * T_ + s0 + col * 8);
        }
        __syncthreads();

        for (int sub = 0; sub < 4; sub++) {
            int sc = s0 + sub * 32;
            if (sc > tmax) break;             // later subs only larger
#pragma unroll
            for (int sh = 0; sh < 2; sh++) {
                int rowb = sub * 32 + sh * 16 + l16;
                short8 b0 = *(const short8*)(Kb + rowb * 72 + quad * 8);
                short8 b1 = *(const short8*)(Kb + rowb * 72 + 32 + quad * 8);
                f32x4 d = (f32x4)(0.f);
                d = __builtin_amdgcn_mfma_f32_16x16x32_bf16(aq0, b0, d, 0, 0, 0);
                d = __builtin_amdgcn_mfma_f32_16x16x32_bf16(aq1, b1, d, 0, 0, 0);
                int s = sc + sh * 16 + l16;   // D: row=t (quad*4+r), col=s (l16)
#pragma unroll
                for (int r = 0; r < 4; r++) {
                    int t = t0w + quad * 4 + r;
                    float p = __expf(d[r] * SC);
                    p = (s <= t) ? p : 0.f;
                    myp[(quad * 4 + r) * 40 + sh * 16 + l16] = f2bf(p);
                }
            }
            // wave-private LDS round-trip: C-layout -> A-layout
            asm volatile("s_waitcnt lgkmcnt(0)" ::: "memory");
            short8 ap = *(const short8*)(myp + l16 * 40 + quad * 8);
#pragma unroll
            for (int h4 = 0; h4 < 4; h4++) {
                short8 bv = *(const short8*)(Vb + (h4 * 16 + l16) * 136 + sub * 32 + quad * 8);
                f32x4 acc = (h4 == 0) ? o0 : (h4 == 1) ? o1 : (h4 == 2) ? o2 : o3;
                acc = __builtin_amdgcn_mfma_f32_16x16x32_bf16(ap, bv, acc, 0, 0, 0);
                if (h4 == 0) o0 = acc; else if (h4 == 1) o1 = acc; else if (h4 == 2) o2 = acc; else o3 = acc;
            }
        }
        __syncthreads();
    }

    f32x4 oo[4] = {o0, o1, o2, o3};
#pragma unroll
    for (int h4 = 0; h4 < 4; h4++)
#pragma unroll
        for (int r = 0; r < 4; r++) {
            int t = t0w + quad * 4 + r;
            atomicAdd(&out[bq + (long)t * DH + h4 * 16 + l16], oo[h4][r]);
        }
}

extern "C" void kernel_launch(void* const* d_in, const int* in_sizes, int n_in,
                              void* d_out, int out_size, void* d_ws, size_t ws_size,
                              hipStream_t stream) {
    const float* x  = (const float*)d_in[0];
    const float* Wq = (const float*)d_in[1];
    const float* Wk = (const float*)d_in[2];
    const float* Wv = (const float*)d_in[3];
    float* out = (float*)d_out;

    char* ws = (char*)d_ws;
    short* qb   = (short*)(ws);                    // 2 MB  bf16 [B,T,64]
    short* kb   = (short*)(ws + (2l << 20));       // 2 MB  bf16 [B,T,64]
    short* vb   = (short*)(ws + (4l << 20));       // 2 MB  bf16 [B,T,64]
    short* vT   = (short*)(ws + (6l << 20));       // 2 MB  bf16 [B,64,T]
    short* wb   = (short*)(ws + (8l << 20));       // 192 KB bf16 [3,64,512]
    float* lsum = (float*)(ws + (9l << 20));       // 64 KB fp32 [B,T]

    hipMemsetAsync(out, 0, (size_t)out_size * sizeof(float), stream);
    hipMemsetAsync(lsum, 0, (size_t)(B_ * T_) * sizeof(float), stream);

    k_wcvt<<<dim3(48), dim3(256), 0, stream>>>(Wq, Wk, Wv, wb);
    k_proj<<<dim3(3 * B_ * T_ / 64), dim3(256), 0, stream>>>(x, wb, qb, kb, vb);
    k_stats<<<dim3(B_ * 64 * (T_ / CT)), dim3(256), 0, stream>>>(qb, kb, lsum);
    k_vt<<<dim3(B_ * T_ / 64), dim3(256), 0, stream>>>(vb, lsum, vT);
    k_out<<<dim3(B_ * 64 * (T_ / CS)), dim3(256), 0, stream>>>(qb, kb, vT, out);
}